// Round 9
// baseline (1529.130 us; speedup 1.0000x reference)
//
#include <hip/hip_runtime.h>
#include <hip/hip_bf16.h>
#include <math.h>

#define NN 50000
#define EE 800000
#define HD 128   // H*D
#define CAP 80   // max in-degree capacity (Poisson(16); P(deg>80) < 1e-30)
#define BN_EPS 1e-5f
#define NBKT 64  // replicated column-stat buckets

typedef __attribute__((ext_vector_type(8))) short bf16x8;
typedef __attribute__((ext_vector_type(4))) float f32x4;

__device__ __forceinline__ unsigned short f2bf(float f) {
    unsigned u = __float_as_uint(f);
    unsigned rounded = u + 0x7fffu + ((u >> 16) & 1u);
    return (unsigned short)(rounded >> 16);
}
__device__ __forceinline__ float bflo(unsigned u) { return __uint_as_float(u << 16); }
__device__ __forceinline__ float bfhi(unsigned u) { return __uint_as_float(u & 0xffff0000u); }

// ---- prep: W cast + zero {deg, stat buckets, ticket} in one launch -------
#define W_ITEMS 65536
#define DEG_OFF 65536
#define COL_OFF (65536 + NN)              // 115536
#define COL_ITEMS (2 * NBKT * HD)         // 16384
#define TICKET_IDX (COL_OFF + COL_ITEMS)  // 131920
#define PREP_TOTAL (TICKET_IDX + 1)

__global__ __launch_bounds__(256) void prep_kernel(
    const float* __restrict__ Wq, const float* __restrict__ Wk,
    const float* __restrict__ Wv, const float* __restrict__ Ws,
    unsigned short* __restrict__ Wt, int* __restrict__ deg,
    float* __restrict__ colrep, int* __restrict__ ticket)
{
    int i = blockIdx.x * 256 + threadIdx.x;
    if (i < W_ITEMS) {
        int n = i >> 7;
        int k = i & 127;
        const float* W = (n < 128) ? Wq : (n < 256) ? Wk : (n < 384) ? Wv : Ws;
        Wt[n * 128 + k] = f2bf(W[k * 128 + (n & 127)]);
    } else if (i < COL_OFF) {
        deg[i - DEG_OFF] = 0;
    } else if (i < TICKET_IDX) {
        colrep[i - COL_OFF] = 0.f;
    } else if (i == TICKET_IDX) {
        *ticket = 0;
    }
}

// ---- gemm + fused edge scatter (independent chains overlap) --------------
__global__ __launch_bounds__(256) void gemm_csr_kernel(
    const float* __restrict__ x, const unsigned short* __restrict__ Wt,
    const float* __restrict__ bq, const float* __restrict__ bk,
    const float* __restrict__ bv, const float* __restrict__ bs,
    unsigned short* __restrict__ Qh, unsigned short* __restrict__ Kh,
    unsigned short* __restrict__ Vh, unsigned short* __restrict__ Sh,
    const int* __restrict__ ei, int* __restrict__ deg,
    unsigned short* __restrict__ slots)
{
    __shared__ __align__(16) unsigned short xs[32 * 136];
    int t = threadIdx.x;
    int row0 = blockIdx.x * 32;

    // --- CSR scatter: 2 edges/thread; atomic+scatter latency hides under MFMA
    {
        int e = blockIdx.x * 512 + t;
        #pragma unroll
        for (int rep = 0; rep < 2; ++rep, e += 256) {
            if (e < EE) {
                int src = ei[e];
                int dst = ei[EE + e];
                if ((unsigned)dst < NN) {
                    int slot = atomicAdd(&deg[dst], 1);
                    if (slot < CAP) slots[dst * CAP + slot] = (unsigned short)src;
                }
            }
        }
    }

    // --- stage + cast x tile (32x128 fp32 -> bf16 LDS, row stride 136)
    #pragma unroll
    for (int it = 0; it < 2; ++it) {
        int r = (t >> 4) + it * 16;
        int seg = t & 15;
        int grow = row0 + r;
        uint4 packed;
        if (grow < NN) {
            const float4* p = (const float4*)&x[grow * 128 + seg * 8];
            float4 f0 = p[0], f1 = p[1];
            packed.x = ((unsigned)f2bf(f0.y) << 16) | f2bf(f0.x);
            packed.y = ((unsigned)f2bf(f0.w) << 16) | f2bf(f0.z);
            packed.z = ((unsigned)f2bf(f1.y) << 16) | f2bf(f1.x);
            packed.w = ((unsigned)f2bf(f1.w) << 16) | f2bf(f1.z);
        } else {
            packed = make_uint4(0, 0, 0, 0);
        }
        *(uint4*)&xs[r * 136 + seg * 8] = packed;
    }
    __syncthreads();

    int wave = t >> 6;      // 0..3 -> Wq,Wk,Wv,Ws
    int lane = t & 63;
    int quad = lane >> 4;
    int l15  = lane & 15;
    const unsigned short* Wtm = Wt + wave * 128 * 128;

    f32x4 acc[2][8];
    #pragma unroll
    for (int mt = 0; mt < 2; ++mt)
        #pragma unroll
        for (int nt = 0; nt < 8; ++nt)
            acc[mt][nt] = (f32x4){0.f, 0.f, 0.f, 0.f};

    #pragma unroll
    for (int kk = 0; kk < 4; ++kk) {
        bf16x8 bfrag[8];
        #pragma unroll
        for (int nt = 0; nt < 8; ++nt)
            bfrag[nt] = *(const bf16x8*)&Wtm[(nt * 16 + l15) * 128 + kk * 32 + quad * 8];
        #pragma unroll
        for (int mt = 0; mt < 2; ++mt) {
            bf16x8 afrag = *(const bf16x8*)&xs[(mt * 16 + l15) * 136 + kk * 32 + quad * 8];
            #pragma unroll
            for (int nt = 0; nt < 8; ++nt)
                acc[mt][nt] = __builtin_amdgcn_mfma_f32_16x16x32_bf16(
                    afrag, bfrag[nt], acc[mt][nt], 0, 0, 0);
        }
    }

    const float* biasPtr = (wave == 0) ? bq : (wave == 1) ? bk : (wave == 2) ? bv : bs;
    unsigned short* D = (wave == 0) ? Qh : (wave == 1) ? Kh : (wave == 2) ? Vh : Sh;
    float bias[8];
    #pragma unroll
    for (int nt = 0; nt < 8; ++nt) bias[nt] = biasPtr[nt * 16 + l15];

    #pragma unroll
    for (int mt = 0; mt < 2; ++mt)
        #pragma unroll
        for (int r = 0; r < 4; ++r) {
            int row = row0 + mt * 16 + quad * 4 + r;
            if (row < NN) {
                #pragma unroll
                for (int nt = 0; nt < 8; ++nt)
                    D[row * HD + nt * 16 + l15] = f2bf(acc[mt][nt][r] + bias[nt]);
            }
        }
}

// ---- Fused attention + column stats + last-block BN-coef finalize --------
// One wave per dst; 4 edges/iter; 16 lanes/edge; lane holds 8 dims (uint4).
// NO max subtraction (logits bounded; shift cancels exactly).
__global__ __launch_bounds__(256) void attn_fused_kernel(
    const uint4* __restrict__ Qp, const uint4* __restrict__ Kp,
    const uint4* __restrict__ Vp, const uint4* __restrict__ Sp,
    const int* __restrict__ deg, const unsigned short* __restrict__ slots,
    float* __restrict__ out, float* __restrict__ colrep,
    int* __restrict__ ticket,
    const float* __restrict__ gamma, const float* __restrict__ beta,
    float* __restrict__ scale, float* __restrict__ shift)
{
    __shared__ float bsum[4][128];
    __shared__ float bsq[4][128];
    __shared__ int lastFlag;

    int t = threadIdx.x;
    int wave = t >> 6;
    int lane = t & 63;
    int g    = lane >> 4;        // edge slot 0..3
    int sub  = lane & 15;        // dim chunk: dims [sub*8, sub*8+8)
    int dst = blockIdx.x * 4 + wave;      // NN % 4 == 0

    int cnt = deg[dst];
    cnt = (cnt < 0) ? 0 : (cnt > CAP ? CAP : cnt);   // defensive clamp
    int base = dst * CAP;

    const float SCL = 0.125f * 1.4426950408889634f;  // fold /sqrt(64) + log2e
    uint4 qu = Qp[dst * 16 + sub];
    float q0 = bflo(qu.x) * SCL, q1 = bfhi(qu.x) * SCL;
    float q2 = bflo(qu.y) * SCL, q3 = bfhi(qu.y) * SCL;
    float q4 = bflo(qu.z) * SCL, q5 = bfhi(qu.z) * SCL;
    float q6 = bflo(qu.w) * SCL, q7 = bfhi(qu.w) * SCL;

    float den = 0.f;
    float a0=0.f,a1=0.f,a2=0.f,a3=0.f,a4=0.f,a5=0.f,a6=0.f,a7=0.f;

    for (int c0 = 0; c0 < cnt; c0 += 64) {
        int nload = cnt - c0; if (nload > 64) nload = 64;
        int ll = lane < (nload - 1) ? lane : (nload - 1);
        int sidx = (int)slots[base + c0 + ll];
        if ((unsigned)sidx >= NN) sidx = 0;            // defensive clamp
        int nquad = (nload + 3) >> 2;

        int s0 = __shfl(sidx, g, 64);
        uint4 ku = Kp[s0 * 16 + sub];
        uint4 vu = Vp[s0 * 16 + sub];
        bool valid = (g < nload);

        for (int i = 0; i < nquad; ++i) {
            uint4 nku = ku, nvu = vu;
            bool nvalid = false;
            if (i + 1 < nquad) {
                int jn = (i + 1) * 4 + g;              // <= 63
                int sn = __shfl(sidx, jn, 64);
                nvalid = (jn < nload);
                nku = Kp[sn * 16 + sub];
                nvu = Vp[sn * 16 + sub];
            }
            float p;
            p = q0 * bflo(ku.x);
            p = fmaf(q1, bfhi(ku.x), p);
            p = fmaf(q2, bflo(ku.y), p);
            p = fmaf(q3, bfhi(ku.y), p);
            p = fmaf(q4, bflo(ku.z), p);
            p = fmaf(q5, bfhi(ku.z), p);
            p = fmaf(q6, bflo(ku.w), p);
            p = fmaf(q7, bfhi(ku.w), p);
            p += __shfl_xor(p, 1, 64);
            p += __shfl_xor(p, 2, 64);
            p += __shfl_xor(p, 4, 64);   // lanes 0-7: head0, 8-15: head1
            float w = valid ? exp2f(p) : 0.f;
            a0 = fmaf(w, bflo(vu.x), a0);
            a1 = fmaf(w, bfhi(vu.x), a1);
            a2 = fmaf(w, bflo(vu.y), a2);
            a3 = fmaf(w, bfhi(vu.y), a3);
            a4 = fmaf(w, bflo(vu.z), a4);
            a5 = fmaf(w, bfhi(vu.z), a5);
            a6 = fmaf(w, bflo(vu.w), a6);
            a7 = fmaf(w, bfhi(vu.w), a7);
            den += w;
            ku = nku; vu = nvu; valid = nvalid;
        }
    }

    den += __shfl_xor(den, 16, 64);
    den += __shfl_xor(den, 32, 64);
    a0 += __shfl_xor(a0, 16, 64); a0 += __shfl_xor(a0, 32, 64);
    a1 += __shfl_xor(a1, 16, 64); a1 += __shfl_xor(a1, 32, 64);
    a2 += __shfl_xor(a2, 16, 64); a2 += __shfl_xor(a2, 32, 64);
    a3 += __shfl_xor(a3, 16, 64); a3 += __shfl_xor(a3, 32, 64);
    a4 += __shfl_xor(a4, 16, 64); a4 += __shfl_xor(a4, 32, 64);
    a5 += __shfl_xor(a5, 16, 64); a5 += __shfl_xor(a5, 32, 64);
    a6 += __shfl_xor(a6, 16, 64); a6 += __shfl_xor(a6, 32, 64);
    a7 += __shfl_xor(a7, 16, 64); a7 += __shfl_xor(a7, 32, 64);

    if (g == 0) {
        float inv = 1.0f / fmaxf(den, 1e-16f);
        uint4 sk = Sp[dst * 16 + sub];
        float4 o1, o2;
        o1.x = fmaf(a0, inv, bflo(sk.x));
        o1.y = fmaf(a1, inv, bfhi(sk.x));
        o1.z = fmaf(a2, inv, bflo(sk.y));
        o1.w = fmaf(a3, inv, bfhi(sk.y));
        o2.x = fmaf(a4, inv, bflo(sk.z));
        o2.y = fmaf(a5, inv, bfhi(sk.z));
        o2.z = fmaf(a6, inv, bflo(sk.w));
        o2.w = fmaf(a7, inv, bfhi(sk.w));
        float4* op = (float4*)&out[dst * HD + sub * 8];
        op[0] = o1;
        op[1] = o2;
        // column-stat contributions into LDS
        int cbase = sub * 8;
        bsum[wave][cbase+0] = o1.x; bsq[wave][cbase+0] = o1.x*o1.x;
        bsum[wave][cbase+1] = o1.y; bsq[wave][cbase+1] = o1.y*o1.y;
        bsum[wave][cbase+2] = o1.z; bsq[wave][cbase+2] = o1.z*o1.z;
        bsum[wave][cbase+3] = o1.w; bsq[wave][cbase+3] = o1.w*o1.w;
        bsum[wave][cbase+4] = o2.x; bsq[wave][cbase+4] = o2.x*o2.x;
        bsum[wave][cbase+5] = o2.y; bsq[wave][cbase+5] = o2.y*o2.y;
        bsum[wave][cbase+6] = o2.z; bsq[wave][cbase+6] = o2.z*o2.z;
        bsum[wave][cbase+7] = o2.w; bsq[wave][cbase+7] = o2.w*o2.w;
    }
    __syncthreads();

    // block-level stats -> replicated buckets (contention / NBKT)
    if (t < 128) {
        float s = bsum[0][t] + bsum[1][t] + bsum[2][t] + bsum[3][t];
        float q = bsq[0][t]  + bsq[1][t]  + bsq[2][t]  + bsq[3][t];
        int bkt = blockIdx.x & (NBKT - 1);
        atomicAdd(&colrep[bkt * HD + t], s);
        atomicAdd(&colrep[NBKT * HD + bkt * HD + t], q);
    }

    // last-block-done: reduce buckets, emit BN scale/shift
    __threadfence();
    if (t == 0) {
        int old = atomicAdd(ticket, 1);
        lastFlag = (old == (int)gridDim.x - 1);
    }
    __syncthreads();
    if (lastFlag) {
        __threadfence();
        if (t < 128) {
            float s = 0.f, q = 0.f;
            for (int r = 0; r < NBKT; ++r) {
                s += colrep[r * HD + t];
                q += colrep[NBKT * HD + r * HD + t];
            }
            const float invN = 1.0f / (float)NN;
            float mean = s * invN;
            float var  = q * invN - mean * mean;
            float sc = gamma[t] * rsqrtf(var + BN_EPS);
            scale[t] = sc;
            shift[t] = beta[t] - mean * sc;
        }
    }
}

// ---- BN apply + Mish, in place, float4 -----------------------------------
// mish(y) = y * tanh(softplus(y)) = y * ((1+e^y)^2 - 1) / ((1+e^y)^2 + 1)
__global__ __launch_bounds__(256) void bn_mish_kernel(
    float4* __restrict__ y, const float4* __restrict__ scale4,
    const float4* __restrict__ shift4)
{
    int i = blockIdx.x * 256 + threadIdx.x;   // NN*32 float4s
    if (i >= NN * 32) return;
    int j = i & 31;
    float4 sc = scale4[j], sh = shift4[j];
    float4 v = y[i];
    float4 o;
    #pragma unroll
    for (int k = 0; k < 4; ++k) {
        float yn = fmaf((&v.x)[k], (&sc.x)[k], (&sh.x)[k]);
        float yc = fminf(yn, 30.f);                        // overflow guard only
        float t1 = 1.f + exp2f(yc * 1.4426950408889634f);  // 1 + e^y
        float t2 = t1 * t1;
        (&o.x)[k] = yn * (t2 - 1.f) / (t2 + 1.f);
    }
    y[i] = o;
}

extern "C" void kernel_launch(void* const* d_in, const int* in_sizes, int n_in,
                              void* d_out, int out_size, void* d_ws, size_t ws_size,
                              hipStream_t stream) {
    const float* x     = (const float*)d_in[0];
    const int*   ei    = (const int*)d_in[1];
    const float* Wq    = (const float*)d_in[2];
    const float* bq    = (const float*)d_in[3];
    const float* Wk    = (const float*)d_in[4];
    const float* bk    = (const float*)d_in[5];
    const float* Wv    = (const float*)d_in[6];
    const float* bv    = (const float*)d_in[7];
    const float* Wsk   = (const float*)d_in[8];
    const float* bsk   = (const float*)d_in[9];
    const float* gamma = (const float*)d_in[10];
    const float* beta  = (const float*)d_in[11];
    float* out = (float*)d_out;

    char* ws = (char*)d_ws;
    unsigned short* Qh = (unsigned short*)ws;     ws += (size_t)NN * HD * 2;
    unsigned short* Kh = (unsigned short*)ws;     ws += (size_t)NN * HD * 2;
    unsigned short* Vh = (unsigned short*)ws;     ws += (size_t)NN * HD * 2;
    unsigned short* Sh = (unsigned short*)ws;     ws += (size_t)NN * HD * 2;
    unsigned short* Wt = (unsigned short*)ws;     ws += (size_t)512 * 128 * 2;
    int* deg       = (int*)ws;                    ws += (size_t)NN * 4;
    float* colrep  = (float*)ws;                  ws += (size_t)2 * NBKT * HD * 4;
    float* scale   = (float*)ws;                  ws += HD * 4;
    float* shift   = (float*)ws;                  ws += HD * 4;
    int* ticket    = (int*)ws;                    ws += 256;   // padded
    unsigned short* slots = (unsigned short*)ws;  ws += (size_t)NN * CAP * 2;

    prep_kernel<<<(PREP_TOTAL + 255) / 256, 256, 0, stream>>>(
        Wq, Wk, Wv, Wsk, Wt, deg, colrep, ticket);
    gemm_csr_kernel<<<(NN + 31) / 32, 256, 0, stream>>>(
        x, Wt, bq, bk, bv, bsk, Qh, Kh, Vh, Sh, ei, deg, slots);
    attn_fused_kernel<<<NN / 4, 256, 0, stream>>>(
        (const uint4*)Qh, (const uint4*)Kh, (const uint4*)Vh, (const uint4*)Sh,
        deg, slots, out, colrep, ticket, gamma, beta, scale, shift);
    bn_mish_kernel<<<(NN * 32 + 255) / 256, 256, 0, stream>>>(
        (float4*)out, (const float4*)scale, (const float4*)shift);
}

// Round 10
// 236.328 us; speedup vs baseline: 6.4704x; 6.4704x over previous
//
#include <hip/hip_runtime.h>
#include <hip/hip_bf16.h>
#include <math.h>

#define NN 50000
#define EE 800000
#define HD 128   // H*D
#define CAP 80   // max in-degree capacity (Poisson(16); P(deg>80) < 1e-30)
#define BN_EPS 1e-5f
#define NBKT 64  // replicated column-stat buckets

typedef __attribute__((ext_vector_type(8))) short bf16x8;
typedef __attribute__((ext_vector_type(4))) float f32x4;

__device__ __forceinline__ unsigned short f2bf(float f) {
    unsigned u = __float_as_uint(f);
    unsigned rounded = u + 0x7fffu + ((u >> 16) & 1u);
    return (unsigned short)(rounded >> 16);
}
__device__ __forceinline__ float bflo(unsigned u) { return __uint_as_float(u << 16); }
__device__ __forceinline__ float bfhi(unsigned u) { return __uint_as_float(u & 0xffff0000u); }

// ---- prep: W cast + zero {deg, stat buckets} in one launch ---------------
#define W_ITEMS 65536
#define DEG_OFF 65536
#define COL_OFF (65536 + NN)              // 115536
#define COL_ITEMS (2 * NBKT * HD)         // 16384
#define PREP_TOTAL (COL_OFF + COL_ITEMS)

__global__ __launch_bounds__(256) void prep_kernel(
    const float* __restrict__ Wq, const float* __restrict__ Wk,
    const float* __restrict__ Wv, const float* __restrict__ Ws,
    unsigned short* __restrict__ Wt, int* __restrict__ deg,
    float* __restrict__ colrep)
{
    int i = blockIdx.x * 256 + threadIdx.x;
    if (i < W_ITEMS) {
        int n = i >> 7;
        int k = i & 127;
        const float* W = (n < 128) ? Wq : (n < 256) ? Wk : (n < 384) ? Wv : Ws;
        Wt[n * 128 + k] = f2bf(W[k * 128 + (n & 127)]);
    } else if (i < COL_OFF) {
        deg[i - DEG_OFF] = 0;
    } else if (i < PREP_TOTAL) {
        colrep[i - COL_OFF] = 0.f;
    }
}

// ---- gemm + fused edge scatter (independent chains overlap) --------------
__global__ __launch_bounds__(256) void gemm_csr_kernel(
    const float* __restrict__ x, const unsigned short* __restrict__ Wt,
    const float* __restrict__ bq, const float* __restrict__ bk,
    const float* __restrict__ bv, const float* __restrict__ bs,
    unsigned short* __restrict__ Qh, unsigned short* __restrict__ Kh,
    unsigned short* __restrict__ Vh, unsigned short* __restrict__ Sh,
    const int* __restrict__ ei, int* __restrict__ deg,
    unsigned short* __restrict__ slots)
{
    __shared__ __align__(16) unsigned short xs[32 * 136];
    int t = threadIdx.x;
    int row0 = blockIdx.x * 32;

    // --- CSR scatter: 2 edges/thread; atomic+scatter latency hides under MFMA
    {
        int e = blockIdx.x * 512 + t;
        #pragma unroll
        for (int rep = 0; rep < 2; ++rep, e += 256) {
            if (e < EE) {
                int src = ei[e];
                int dst = ei[EE + e];
                if ((unsigned)dst < NN) {
                    int slot = atomicAdd(&deg[dst], 1);
                    if (slot < CAP) slots[dst * CAP + slot] = (unsigned short)src;
                }
            }
        }
    }

    // --- stage + cast x tile (32x128 fp32 -> bf16 LDS, row stride 136)
    #pragma unroll
    for (int it = 0; it < 2; ++it) {
        int r = (t >> 4) + it * 16;
        int seg = t & 15;
        int grow = row0 + r;
        uint4 packed;
        if (grow < NN) {
            const float4* p = (const float4*)&x[grow * 128 + seg * 8];
            float4 f0 = p[0], f1 = p[1];
            packed.x = ((unsigned)f2bf(f0.y) << 16) | f2bf(f0.x);
            packed.y = ((unsigned)f2bf(f0.w) << 16) | f2bf(f0.z);
            packed.z = ((unsigned)f2bf(f1.y) << 16) | f2bf(f1.x);
            packed.w = ((unsigned)f2bf(f1.w) << 16) | f2bf(f1.z);
        } else {
            packed = make_uint4(0, 0, 0, 0);
        }
        *(uint4*)&xs[r * 136 + seg * 8] = packed;
    }
    __syncthreads();

    int wave = t >> 6;      // 0..3 -> Wq,Wk,Wv,Ws
    int lane = t & 63;
    int quad = lane >> 4;
    int l15  = lane & 15;
    const unsigned short* Wtm = Wt + wave * 128 * 128;

    f32x4 acc[2][8];
    #pragma unroll
    for (int mt = 0; mt < 2; ++mt)
        #pragma unroll
        for (int nt = 0; nt < 8; ++nt)
            acc[mt][nt] = (f32x4){0.f, 0.f, 0.f, 0.f};

    #pragma unroll
    for (int kk = 0; kk < 4; ++kk) {
        bf16x8 bfrag[8];
        #pragma unroll
        for (int nt = 0; nt < 8; ++nt)
            bfrag[nt] = *(const bf16x8*)&Wtm[(nt * 16 + l15) * 128 + kk * 32 + quad * 8];
        #pragma unroll
        for (int mt = 0; mt < 2; ++mt) {
            bf16x8 afrag = *(const bf16x8*)&xs[(mt * 16 + l15) * 136 + kk * 32 + quad * 8];
            #pragma unroll
            for (int nt = 0; nt < 8; ++nt)
                acc[mt][nt] = __builtin_amdgcn_mfma_f32_16x16x32_bf16(
                    afrag, bfrag[nt], acc[mt][nt], 0, 0, 0);
        }
    }

    const float* biasPtr = (wave == 0) ? bq : (wave == 1) ? bk : (wave == 2) ? bv : bs;
    unsigned short* D = (wave == 0) ? Qh : (wave == 1) ? Kh : (wave == 2) ? Vh : Sh;
    float bias[8];
    #pragma unroll
    for (int nt = 0; nt < 8; ++nt) bias[nt] = biasPtr[nt * 16 + l15];

    #pragma unroll
    for (int mt = 0; mt < 2; ++mt)
        #pragma unroll
        for (int r = 0; r < 4; ++r) {
            int row = row0 + mt * 16 + quad * 4 + r;
            if (row < NN) {
                #pragma unroll
                for (int nt = 0; nt < 8; ++nt)
                    D[row * HD + nt * 16 + l15] = f2bf(acc[mt][nt][r] + bias[nt]);
            }
        }
}

// ---- Fused attention + column-stat bucket atomics (NO fence/ticket) ------
// One wave per dst; 4 edges/iter; 16 lanes/edge; lane holds 8 dims (uint4).
// NO max subtraction (logits bounded; shift cancels exactly).
__global__ __launch_bounds__(256) void attn_fused_kernel(
    const uint4* __restrict__ Qp, const uint4* __restrict__ Kp,
    const uint4* __restrict__ Vp, const uint4* __restrict__ Sp,
    const int* __restrict__ deg, const unsigned short* __restrict__ slots,
    float* __restrict__ out, float* __restrict__ colrep)
{
    __shared__ float bsum[4][128];
    __shared__ float bsq[4][128];

    int t = threadIdx.x;
    int wave = t >> 6;
    int lane = t & 63;
    int g    = lane >> 4;        // edge slot 0..3
    int sub  = lane & 15;        // dim chunk: dims [sub*8, sub*8+8)
    int dst = blockIdx.x * 4 + wave;      // NN % 4 == 0

    int cnt = deg[dst];
    cnt = (cnt < 0) ? 0 : (cnt > CAP ? CAP : cnt);   // defensive clamp
    int base = dst * CAP;

    const float SCL = 0.125f * 1.4426950408889634f;  // fold /sqrt(64) + log2e
    uint4 qu = Qp[dst * 16 + sub];
    float q0 = bflo(qu.x) * SCL, q1 = bfhi(qu.x) * SCL;
    float q2 = bflo(qu.y) * SCL, q3 = bfhi(qu.y) * SCL;
    float q4 = bflo(qu.z) * SCL, q5 = bfhi(qu.z) * SCL;
    float q6 = bflo(qu.w) * SCL, q7 = bfhi(qu.w) * SCL;

    float den = 0.f;
    float a0=0.f,a1=0.f,a2=0.f,a3=0.f,a4=0.f,a5=0.f,a6=0.f,a7=0.f;

    for (int c0 = 0; c0 < cnt; c0 += 64) {
        int nload = cnt - c0; if (nload > 64) nload = 64;
        int ll = lane < (nload - 1) ? lane : (nload - 1);
        int sidx = (int)slots[base + c0 + ll];
        if ((unsigned)sidx >= NN) sidx = 0;            // defensive clamp
        int nquad = (nload + 3) >> 2;

        int s0 = __shfl(sidx, g, 64);
        uint4 ku = Kp[s0 * 16 + sub];
        uint4 vu = Vp[s0 * 16 + sub];
        bool valid = (g < nload);

        for (int i = 0; i < nquad; ++i) {
            uint4 nku = ku, nvu = vu;
            bool nvalid = false;
            if (i + 1 < nquad) {
                int jn = (i + 1) * 4 + g;              // <= 63
                int sn = __shfl(sidx, jn, 64);
                nvalid = (jn < nload);
                nku = Kp[sn * 16 + sub];
                nvu = Vp[sn * 16 + sub];
            }
            float p;
            p = q0 * bflo(ku.x);
            p = fmaf(q1, bfhi(ku.x), p);
            p = fmaf(q2, bflo(ku.y), p);
            p = fmaf(q3, bfhi(ku.y), p);
            p = fmaf(q4, bflo(ku.z), p);
            p = fmaf(q5, bfhi(ku.z), p);
            p = fmaf(q6, bflo(ku.w), p);
            p = fmaf(q7, bfhi(ku.w), p);
            p += __shfl_xor(p, 1, 64);
            p += __shfl_xor(p, 2, 64);
            p += __shfl_xor(p, 4, 64);   // lanes 0-7: head0, 8-15: head1
            float w = valid ? exp2f(p) : 0.f;
            a0 = fmaf(w, bflo(vu.x), a0);
            a1 = fmaf(w, bfhi(vu.x), a1);
            a2 = fmaf(w, bflo(vu.y), a2);
            a3 = fmaf(w, bfhi(vu.y), a3);
            a4 = fmaf(w, bflo(vu.z), a4);
            a5 = fmaf(w, bfhi(vu.z), a5);
            a6 = fmaf(w, bflo(vu.w), a6);
            a7 = fmaf(w, bfhi(vu.w), a7);
            den += w;
            ku = nku; vu = nvu; valid = nvalid;
        }
    }

    den += __shfl_xor(den, 16, 64);
    den += __shfl_xor(den, 32, 64);
    a0 += __shfl_xor(a0, 16, 64); a0 += __shfl_xor(a0, 32, 64);
    a1 += __shfl_xor(a1, 16, 64); a1 += __shfl_xor(a1, 32, 64);
    a2 += __shfl_xor(a2, 16, 64); a2 += __shfl_xor(a2, 32, 64);
    a3 += __shfl_xor(a3, 16, 64); a3 += __shfl_xor(a3, 32, 64);
    a4 += __shfl_xor(a4, 16, 64); a4 += __shfl_xor(a4, 32, 64);
    a5 += __shfl_xor(a5, 16, 64); a5 += __shfl_xor(a5, 32, 64);
    a6 += __shfl_xor(a6, 16, 64); a6 += __shfl_xor(a6, 32, 64);
    a7 += __shfl_xor(a7, 16, 64); a7 += __shfl_xor(a7, 32, 64);

    if (g == 0) {
        float inv = 1.0f / fmaxf(den, 1e-16f);
        uint4 sk = Sp[dst * 16 + sub];
        float4 o1, o2;
        o1.x = fmaf(a0, inv, bflo(sk.x));
        o1.y = fmaf(a1, inv, bfhi(sk.x));
        o1.z = fmaf(a2, inv, bflo(sk.y));
        o1.w = fmaf(a3, inv, bfhi(sk.y));
        o2.x = fmaf(a4, inv, bflo(sk.z));
        o2.y = fmaf(a5, inv, bfhi(sk.z));
        o2.z = fmaf(a6, inv, bflo(sk.w));
        o2.w = fmaf(a7, inv, bfhi(sk.w));
        float4* op = (float4*)&out[dst * HD + sub * 8];
        op[0] = o1;
        op[1] = o2;
        int cbase = sub * 8;
        bsum[wave][cbase+0] = o1.x; bsq[wave][cbase+0] = o1.x*o1.x;
        bsum[wave][cbase+1] = o1.y; bsq[wave][cbase+1] = o1.y*o1.y;
        bsum[wave][cbase+2] = o1.z; bsq[wave][cbase+2] = o1.z*o1.z;
        bsum[wave][cbase+3] = o1.w; bsq[wave][cbase+3] = o1.w*o1.w;
        bsum[wave][cbase+4] = o2.x; bsq[wave][cbase+4] = o2.x*o2.x;
        bsum[wave][cbase+5] = o2.y; bsq[wave][cbase+5] = o2.y*o2.y;
        bsum[wave][cbase+6] = o2.z; bsq[wave][cbase+6] = o2.z*o2.z;
        bsum[wave][cbase+7] = o2.w; bsq[wave][cbase+7] = o2.w*o2.w;
    }
    __syncthreads();

    // block-level stats -> replicated buckets (contention / NBKT); no fence
    if (t < 128) {
        float s = bsum[0][t] + bsum[1][t] + bsum[2][t] + bsum[3][t];
        float q = bsq[0][t]  + bsq[1][t]  + bsq[2][t]  + bsq[3][t];
        int bkt = blockIdx.x & (NBKT - 1);
        atomicAdd(&colrep[bkt * HD + t], s);
        atomicAdd(&colrep[NBKT * HD + bkt * HD + t], q);
    }
}

// ---- finalize: reduce buckets -> BN scale/shift (1 block) ----------------
__global__ __launch_bounds__(128) void finalize_kernel(
    const float* __restrict__ colrep,
    const float* __restrict__ gamma, const float* __restrict__ beta,
    float* __restrict__ scale, float* __restrict__ shift)
{
    int t = threadIdx.x;   // 0..127
    float s = 0.f, q = 0.f;
    for (int r = 0; r < NBKT; ++r) {
        s += colrep[r * HD + t];
        q += colrep[NBKT * HD + r * HD + t];
    }
    const float invN = 1.0f / (float)NN;
    float mean = s * invN;
    float var  = q * invN - mean * mean;
    float sc = gamma[t] * rsqrtf(var + BN_EPS);
    scale[t] = sc;
    shift[t] = beta[t] - mean * sc;
}

// ---- BN apply + Mish, in place, float4 -----------------------------------
// mish(y) = y * tanh(softplus(y)) = y * ((1+e^y)^2 - 1) / ((1+e^y)^2 + 1)
__global__ __launch_bounds__(256) void bn_mish_kernel(
    float4* __restrict__ y, const float4* __restrict__ scale4,
    const float4* __restrict__ shift4)
{
    int i = blockIdx.x * 256 + threadIdx.x;   // NN*32 float4s
    if (i >= NN * 32) return;
    int j = i & 31;
    float4 sc = scale4[j], sh = shift4[j];
    float4 v = y[i];
    float4 o;
    #pragma unroll
    for (int k = 0; k < 4; ++k) {
        float yn = fmaf((&v.x)[k], (&sc.x)[k], (&sh.x)[k]);
        float yc = fminf(yn, 30.f);                        // overflow guard only
        float t1 = 1.f + exp2f(yc * 1.4426950408889634f);  // 1 + e^y
        float t2 = t1 * t1;
        (&o.x)[k] = yn * (t2 - 1.f) / (t2 + 1.f);
    }
    y[i] = o;
}

extern "C" void kernel_launch(void* const* d_in, const int* in_sizes, int n_in,
                              void* d_out, int out_size, void* d_ws, size_t ws_size,
                              hipStream_t stream) {
    const float* x     = (const float*)d_in[0];
    const int*   ei    = (const int*)d_in[1];
    const float* Wq    = (const float*)d_in[2];
    const float* bq    = (const float*)d_in[3];
    const float* Wk    = (const float*)d_in[4];
    const float* bk    = (const float*)d_in[5];
    const float* Wv    = (const float*)d_in[6];
    const float* bv    = (const float*)d_in[7];
    const float* Wsk   = (const float*)d_in[8];
    const float* bsk   = (const float*)d_in[9];
    const float* gamma = (const float*)d_in[10];
    const float* beta  = (const float*)d_in[11];
    float* out = (float*)d_out;

    char* ws = (char*)d_ws;
    unsigned short* Qh = (unsigned short*)ws;     ws += (size_t)NN * HD * 2;
    unsigned short* Kh = (unsigned short*)ws;     ws += (size_t)NN * HD * 2;
    unsigned short* Vh = (unsigned short*)ws;     ws += (size_t)NN * HD * 2;
    unsigned short* Sh = (unsigned short*)ws;     ws += (size_t)NN * HD * 2;
    unsigned short* Wt = (unsigned short*)ws;     ws += (size_t)512 * 128 * 2;
    int* deg       = (int*)ws;                    ws += (size_t)NN * 4;
    float* colrep  = (float*)ws;                  ws += (size_t)2 * NBKT * HD * 4;
    float* scale   = (float*)ws;                  ws += HD * 4;
    float* shift   = (float*)ws;                  ws += HD * 4;
    unsigned short* slots = (unsigned short*)ws;  ws += (size_t)NN * CAP * 2;

    prep_kernel<<<(PREP_TOTAL + 255) / 256, 256, 0, stream>>>(
        Wq, Wk, Wv, Wsk, Wt, deg, colrep);
    gemm_csr_kernel<<<(NN + 31) / 32, 256, 0, stream>>>(
        x, Wt, bq, bk, bv, bsk, Qh, Kh, Vh, Sh, ei, deg, slots);
    attn_fused_kernel<<<NN / 4, 256, 0, stream>>>(
        (const uint4*)Qh, (const uint4*)Kh, (const uint4*)Vh, (const uint4*)Sh,
        deg, slots, out, colrep);
    finalize_kernel<<<1, 128, 0, stream>>>(colrep, gamma, beta, scale, shift);
    bn_mish_kernel<<<(NN * 32 + 255) / 256, 256, 0, stream>>>(
        (float4*)out, (const float4*)scale, (const float4*)shift);
}

// Round 11
// 230.458 us; speedup vs baseline: 6.6352x; 1.0255x over previous
//
#include <hip/hip_runtime.h>
#include <hip/hip_bf16.h>
#include <math.h>

#define NN 50000
#define EE 800000
#define HD 128   // H*D
#define CAP 80   // max in-degree capacity (Poisson(16); P(deg>80) < 1e-30)
#define BN_EPS 1e-5f
#define NBKT 64  // replicated column-stat buckets

typedef __attribute__((ext_vector_type(8))) short bf16x8;
typedef __attribute__((ext_vector_type(4))) float f32x4;

__device__ __forceinline__ unsigned short f2bf(float f) {
    unsigned u = __float_as_uint(f);
    unsigned rounded = u + 0x7fffu + ((u >> 16) & 1u);
    return (unsigned short)(rounded >> 16);
}
__device__ __forceinline__ float bflo(unsigned u) { return __uint_as_float(u << 16); }
__device__ __forceinline__ float bfhi(unsigned u) { return __uint_as_float(u & 0xffff0000u); }

// ---- prep: W cast + zero {deg, stat buckets} in one launch ---------------
#define W_ITEMS 65536
#define DEG_OFF 65536
#define COL_OFF (65536 + NN)              // 115536
#define COL_ITEMS (2 * NBKT * HD)         // 16384
#define PREP_TOTAL (COL_OFF + COL_ITEMS)

__global__ __launch_bounds__(256) void prep_kernel(
    const float* __restrict__ Wq, const float* __restrict__ Wk,
    const float* __restrict__ Wv, const float* __restrict__ Ws,
    unsigned short* __restrict__ Wt, int* __restrict__ deg,
    float* __restrict__ colrep)
{
    int i = blockIdx.x * 256 + threadIdx.x;
    if (i < W_ITEMS) {
        int n = i >> 7;
        int k = i & 127;
        const float* W = (n < 128) ? Wq : (n < 256) ? Wk : (n < 384) ? Wv : Ws;
        Wt[n * 128 + k] = f2bf(W[k * 128 + (n & 127)]);
    } else if (i < COL_OFF) {
        deg[i - DEG_OFF] = 0;
    } else if (i < PREP_TOTAL) {
        colrep[i - COL_OFF] = 0.f;
    }
}

// ---- gemm + edge scatter, GRID-level fusion ------------------------------
// Even blocks: pure MFMA GEMM (32 rows x 512 cols). Odd blocks: pure edge
// scatter (512 edges, early return). Role is block-uniform -> barrier clean.
// Interleaving makes both types co-resident: scatter latency hides under
// the GEMM blocks' compute instead of serializing inside one block (R10 bug).
__global__ __launch_bounds__(256) void gemm_csr_kernel(
    const float* __restrict__ x, const unsigned short* __restrict__ Wt,
    const float* __restrict__ bq, const float* __restrict__ bk,
    const float* __restrict__ bv, const float* __restrict__ bs,
    unsigned short* __restrict__ Qh, unsigned short* __restrict__ Kh,
    unsigned short* __restrict__ Vh, unsigned short* __restrict__ Sh,
    const int* __restrict__ ei, int* __restrict__ deg,
    unsigned short* __restrict__ slots)
{
    __shared__ __align__(16) unsigned short xs[32 * 136];
    int t = threadIdx.x;
    int blk = blockIdx.x >> 1;

    if (blockIdx.x & 1) {
        // ---- scatter role: 512 edges, then exit ----
        int e = blk * 512 + t;
        #pragma unroll
        for (int rep = 0; rep < 2; ++rep, e += 256) {
            if (e < EE) {
                int src = ei[e];
                int dst = ei[EE + e];
                if ((unsigned)dst < NN) {
                    int slot = atomicAdd(&deg[dst], 1);
                    if (slot < CAP) slots[dst * CAP + slot] = (unsigned short)src;
                }
            }
        }
        return;
    }

    // ---- GEMM role ----
    int row0 = blk * 32;

    #pragma unroll
    for (int it = 0; it < 2; ++it) {
        int r = (t >> 4) + it * 16;
        int seg = t & 15;
        int grow = row0 + r;
        uint4 packed;
        if (grow < NN) {
            const float4* p = (const float4*)&x[grow * 128 + seg * 8];
            float4 f0 = p[0], f1 = p[1];
            packed.x = ((unsigned)f2bf(f0.y) << 16) | f2bf(f0.x);
            packed.y = ((unsigned)f2bf(f0.w) << 16) | f2bf(f0.z);
            packed.z = ((unsigned)f2bf(f1.y) << 16) | f2bf(f1.x);
            packed.w = ((unsigned)f2bf(f1.w) << 16) | f2bf(f1.z);
        } else {
            packed = make_uint4(0, 0, 0, 0);
        }
        *(uint4*)&xs[r * 136 + seg * 8] = packed;
    }
    __syncthreads();

    int wave = t >> 6;      // 0..3 -> Wq,Wk,Wv,Ws
    int lane = t & 63;
    int quad = lane >> 4;
    int l15  = lane & 15;
    const unsigned short* Wtm = Wt + wave * 128 * 128;

    f32x4 acc[2][8];
    #pragma unroll
    for (int mt = 0; mt < 2; ++mt)
        #pragma unroll
        for (int nt = 0; nt < 8; ++nt)
            acc[mt][nt] = (f32x4){0.f, 0.f, 0.f, 0.f};

    #pragma unroll
    for (int kk = 0; kk < 4; ++kk) {
        bf16x8 bfrag[8];
        #pragma unroll
        for (int nt = 0; nt < 8; ++nt)
            bfrag[nt] = *(const bf16x8*)&Wtm[(nt * 16 + l15) * 128 + kk * 32 + quad * 8];
        #pragma unroll
        for (int mt = 0; mt < 2; ++mt) {
            bf16x8 afrag = *(const bf16x8*)&xs[(mt * 16 + l15) * 136 + kk * 32 + quad * 8];
            #pragma unroll
            for (int nt = 0; nt < 8; ++nt)
                acc[mt][nt] = __builtin_amdgcn_mfma_f32_16x16x32_bf16(
                    afrag, bfrag[nt], acc[mt][nt], 0, 0, 0);
        }
    }

    const float* biasPtr = (wave == 0) ? bq : (wave == 1) ? bk : (wave == 2) ? bv : bs;
    unsigned short* D = (wave == 0) ? Qh : (wave == 1) ? Kh : (wave == 2) ? Vh : Sh;
    float bias[8];
    #pragma unroll
    for (int nt = 0; nt < 8; ++nt) bias[nt] = biasPtr[nt * 16 + l15];

    #pragma unroll
    for (int mt = 0; mt < 2; ++mt)
        #pragma unroll
        for (int r = 0; r < 4; ++r) {
            int row = row0 + mt * 16 + quad * 4 + r;
            if (row < NN) {
                #pragma unroll
                for (int nt = 0; nt < 8; ++nt)
                    D[row * HD + nt * 16 + l15] = f2bf(acc[mt][nt][r] + bias[nt]);
            }
        }
}

// ---- Fused attention + column-stat bucket atomics (NO fence/ticket) ------
// One wave per dst; 4 edges/iter; 16 lanes/edge; lane holds 8 dims (uint4).
// NO max subtraction (logits bounded; shift cancels exactly).
__global__ __launch_bounds__(256) void attn_fused_kernel(
    const uint4* __restrict__ Qp, const uint4* __restrict__ Kp,
    const uint4* __restrict__ Vp, const uint4* __restrict__ Sp,
    const int* __restrict__ deg, const unsigned short* __restrict__ slots,
    float* __restrict__ out, float* __restrict__ colrep)
{
    __shared__ float bsum[4][128];
    __shared__ float bsq[4][128];

    int t = threadIdx.x;
    int wave = t >> 6;
    int lane = t & 63;
    int g    = lane >> 4;        // edge slot 0..3
    int sub  = lane & 15;        // dim chunk: dims [sub*8, sub*8+8)
    int dst = blockIdx.x * 4 + wave;      // NN % 4 == 0

    int cnt = deg[dst];
    cnt = (cnt < 0) ? 0 : (cnt > CAP ? CAP : cnt);   // defensive clamp
    int base = dst * CAP;

    const float SCL = 0.125f * 1.4426950408889634f;  // fold /sqrt(64) + log2e
    uint4 qu = Qp[dst * 16 + sub];
    float q0 = bflo(qu.x) * SCL, q1 = bfhi(qu.x) * SCL;
    float q2 = bflo(qu.y) * SCL, q3 = bfhi(qu.y) * SCL;
    float q4 = bflo(qu.z) * SCL, q5 = bfhi(qu.z) * SCL;
    float q6 = bflo(qu.w) * SCL, q7 = bfhi(qu.w) * SCL;

    float den = 0.f;
    float a0=0.f,a1=0.f,a2=0.f,a3=0.f,a4=0.f,a5=0.f,a6=0.f,a7=0.f;

    for (int c0 = 0; c0 < cnt; c0 += 64) {
        int nload = cnt - c0; if (nload > 64) nload = 64;
        int ll = lane < (nload - 1) ? lane : (nload - 1);
        int sidx = (int)slots[base + c0 + ll];
        if ((unsigned)sidx >= NN) sidx = 0;            // defensive clamp
        int nquad = (nload + 3) >> 2;

        int s0 = __shfl(sidx, g, 64);
        uint4 ku = Kp[s0 * 16 + sub];
        uint4 vu = Vp[s0 * 16 + sub];
        bool valid = (g < nload);

        for (int i = 0; i < nquad; ++i) {
            uint4 nku = ku, nvu = vu;
            bool nvalid = false;
            if (i + 1 < nquad) {
                int jn = (i + 1) * 4 + g;              // <= 63
                int sn = __shfl(sidx, jn, 64);
                nvalid = (jn < nload);
                nku = Kp[sn * 16 + sub];
                nvu = Vp[sn * 16 + sub];
            }
            float p;
            p = q0 * bflo(ku.x);
            p = fmaf(q1, bfhi(ku.x), p);
            p = fmaf(q2, bflo(ku.y), p);
            p = fmaf(q3, bfhi(ku.y), p);
            p = fmaf(q4, bflo(ku.z), p);
            p = fmaf(q5, bfhi(ku.z), p);
            p = fmaf(q6, bflo(ku.w), p);
            p = fmaf(q7, bfhi(ku.w), p);
            p += __shfl_xor(p, 1, 64);
            p += __shfl_xor(p, 2, 64);
            p += __shfl_xor(p, 4, 64);   // lanes 0-7: head0, 8-15: head1
            float w = valid ? exp2f(p) : 0.f;
            a0 = fmaf(w, bflo(vu.x), a0);
            a1 = fmaf(w, bfhi(vu.x), a1);
            a2 = fmaf(w, bflo(vu.y), a2);
            a3 = fmaf(w, bfhi(vu.y), a3);
            a4 = fmaf(w, bflo(vu.z), a4);
            a5 = fmaf(w, bfhi(vu.z), a5);
            a6 = fmaf(w, bflo(vu.w), a6);
            a7 = fmaf(w, bfhi(vu.w), a7);
            den += w;
            ku = nku; vu = nvu; valid = nvalid;
        }
    }

    den += __shfl_xor(den, 16, 64);
    den += __shfl_xor(den, 32, 64);
    a0 += __shfl_xor(a0, 16, 64); a0 += __shfl_xor(a0, 32, 64);
    a1 += __shfl_xor(a1, 16, 64); a1 += __shfl_xor(a1, 32, 64);
    a2 += __shfl_xor(a2, 16, 64); a2 += __shfl_xor(a2, 32, 64);
    a3 += __shfl_xor(a3, 16, 64); a3 += __shfl_xor(a3, 32, 64);
    a4 += __shfl_xor(a4, 16, 64); a4 += __shfl_xor(a4, 32, 64);
    a5 += __shfl_xor(a5, 16, 64); a5 += __shfl_xor(a5, 32, 64);
    a6 += __shfl_xor(a6, 16, 64); a6 += __shfl_xor(a6, 32, 64);
    a7 += __shfl_xor(a7, 16, 64); a7 += __shfl_xor(a7, 32, 64);

    if (g == 0) {
        float inv = 1.0f / fmaxf(den, 1e-16f);
        uint4 sk = Sp[dst * 16 + sub];
        float4 o1, o2;
        o1.x = fmaf(a0, inv, bflo(sk.x));
        o1.y = fmaf(a1, inv, bfhi(sk.x));
        o1.z = fmaf(a2, inv, bflo(sk.y));
        o1.w = fmaf(a3, inv, bfhi(sk.y));
        o2.x = fmaf(a4, inv, bflo(sk.z));
        o2.y = fmaf(a5, inv, bfhi(sk.z));
        o2.z = fmaf(a6, inv, bflo(sk.w));
        o2.w = fmaf(a7, inv, bfhi(sk.w));
        float4* op = (float4*)&out[dst * HD + sub * 8];
        op[0] = o1;
        op[1] = o2;
        int cbase = sub * 8;
        bsum[wave][cbase+0] = o1.x; bsq[wave][cbase+0] = o1.x*o1.x;
        bsum[wave][cbase+1] = o1.y; bsq[wave][cbase+1] = o1.y*o1.y;
        bsum[wave][cbase+2] = o1.z; bsq[wave][cbase+2] = o1.z*o1.z;
        bsum[wave][cbase+3] = o1.w; bsq[wave][cbase+3] = o1.w*o1.w;
        bsum[wave][cbase+4] = o2.x; bsq[wave][cbase+4] = o2.x*o2.x;
        bsum[wave][cbase+5] = o2.y; bsq[wave][cbase+5] = o2.y*o2.y;
        bsum[wave][cbase+6] = o2.z; bsq[wave][cbase+6] = o2.z*o2.z;
        bsum[wave][cbase+7] = o2.w; bsq[wave][cbase+7] = o2.w*o2.w;
    }
    __syncthreads();

    // block-level stats -> replicated buckets (contention / NBKT); no fence
    if (t < 128) {
        float s = bsum[0][t] + bsum[1][t] + bsum[2][t] + bsum[3][t];
        float q = bsq[0][t]  + bsq[1][t]  + bsq[2][t]  + bsq[3][t];
        int bkt = blockIdx.x & (NBKT - 1);
        atomicAdd(&colrep[bkt * HD + t], s);
        atomicAdd(&colrep[NBKT * HD + bkt * HD + t], q);
    }
}

// ---- finalize: reduce buckets -> BN scale/shift (1 block) ----------------
__global__ __launch_bounds__(128) void finalize_kernel(
    const float* __restrict__ colrep,
    const float* __restrict__ gamma, const float* __restrict__ beta,
    float* __restrict__ scale, float* __restrict__ shift)
{
    int t = threadIdx.x;   // 0..127
    float s = 0.f, q = 0.f;
    for (int r = 0; r < NBKT; ++r) {
        s += colrep[r * HD + t];
        q += colrep[NBKT * HD + r * HD + t];
    }
    const float invN = 1.0f / (float)NN;
    float mean = s * invN;
    float var  = q * invN - mean * mean;
    float sc = gamma[t] * rsqrtf(var + BN_EPS);
    scale[t] = sc;
    shift[t] = beta[t] - mean * sc;
}

// ---- BN apply + Mish, in place, float4 -----------------------------------
// mish(y) = y * tanh(softplus(y)) = y * ((1+e^y)^2 - 1) / ((1+e^y)^2 + 1)
__global__ __launch_bounds__(256) void bn_mish_kernel(
    float4* __restrict__ y, const float4* __restrict__ scale4,
    const float4* __restrict__ shift4)
{
    int i = blockIdx.x * 256 + threadIdx.x;   // NN*32 float4s
    if (i >= NN * 32) return;
    int j = i & 31;
    float4 sc = scale4[j], sh = shift4[j];
    float4 v = y[i];
    float4 o;
    #pragma unroll
    for (int k = 0; k < 4; ++k) {
        float yn = fmaf((&v.x)[k], (&sc.x)[k], (&sh.x)[k]);
        float yc = fminf(yn, 30.f);                        // overflow guard only
        float t1 = 1.f + exp2f(yc * 1.4426950408889634f);  // 1 + e^y
        float t2 = t1 * t1;
        (&o.x)[k] = yn * (t2 - 1.f) / (t2 + 1.f);
    }
    y[i] = o;
}

extern "C" void kernel_launch(void* const* d_in, const int* in_sizes, int n_in,
                              void* d_out, int out_size, void* d_ws, size_t ws_size,
                              hipStream_t stream) {
    const float* x     = (const float*)d_in[0];
    const int*   ei    = (const int*)d_in[1];
    const float* Wq    = (const float*)d_in[2];
    const float* bq    = (const float*)d_in[3];
    const float* Wk    = (const float*)d_in[4];
    const float* bk    = (const float*)d_in[5];
    const float* Wv    = (const float*)d_in[6];
    const float* bv    = (const float*)d_in[7];
    const float* Wsk   = (const float*)d_in[8];
    const float* bsk   = (const float*)d_in[9];
    const float* gamma = (const float*)d_in[10];
    const float* beta  = (const float*)d_in[11];
    float* out = (float*)d_out;

    char* ws = (char*)d_ws;
    unsigned short* Qh = (unsigned short*)ws;     ws += (size_t)NN * HD * 2;
    unsigned short* Kh = (unsigned short*)ws;     ws += (size_t)NN * HD * 2;
    unsigned short* Vh = (unsigned short*)ws;     ws += (size_t)NN * HD * 2;
    unsigned short* Sh = (unsigned short*)ws;     ws += (size_t)NN * HD * 2;
    unsigned short* Wt = (unsigned short*)ws;     ws += (size_t)512 * 128 * 2;
    int* deg       = (int*)ws;                    ws += (size_t)NN * 4;
    float* colrep  = (float*)ws;                  ws += (size_t)2 * NBKT * HD * 4;
    float* scale   = (float*)ws;                  ws += HD * 4;
    float* shift   = (float*)ws;                  ws += HD * 4;
    unsigned short* slots = (unsigned short*)ws;  ws += (size_t)NN * CAP * 2;

    const int GB = (NN + 31) / 32;          // 1563 gemm blocks
    const int SB = (EE + 511) / 512;        // 1563 scatter blocks (== GB)

    prep_kernel<<<(PREP_TOTAL + 255) / 256, 256, 0, stream>>>(
        Wq, Wk, Wv, Wsk, Wt, deg, colrep);
    gemm_csr_kernel<<<GB + SB, 256, 0, stream>>>(
        x, Wt, bq, bk, bv, bsk, Qh, Kh, Vh, Sh, ei, deg, slots);
    attn_fused_kernel<<<NN / 4, 256, 0, stream>>>(
        (const uint4*)Qh, (const uint4*)Kh, (const uint4*)Vh, (const uint4*)Sh,
        deg, slots, out, colrep);
    finalize_kernel<<<1, 128, 0, stream>>>(colrep, gamma, beta, scale, shift);
    bn_mish_kernel<<<(NN * 32 + 255) / 256, 256, 0, stream>>>(
        (float4*)out, (const float4*)scale, (const float4*)shift);
}